// Round 7
// baseline (18415.778 us; speedup 1.0000x reference)
//
#include <hip/hip_runtime.h>
#include <hip/hip_fp16.h>
#include <math.h>

#define TT 833          // output timesteps
#define GDIM 1024       // 4*H gates

__device__ __forceinline__ float sigm(float x){ return 1.f/(1.f+expf(-x)); }

// ---------------- level smoothing scan ----------------
__global__ void levels_k(const float* __restrict__ train, const float* __restrict__ ism,
                         float* __restrict__ levs){
  int b = threadIdx.x;
  if (b >= 32) return;
  float a = 1.f/(1.f+expf(-ism[0]));
  const float* tr = train + b*1024;
  float* lv = levs + b*1024;
  float lev = fmaxf(tr[0], 0.1f);
  lv[0] = lev;
  for (int t = 1; t < 1024; ++t){
    lev = fmaxf(a*tr[t] + (1.f-a)*lev, 0.1f);
    lv[t] = lev;
  }
}

// ---------------- normalized input windows x0[t*32+b][168] ----------------
__global__ void win_x_k(const float* __restrict__ train, const float* __restrict__ levs,
                        float* __restrict__ x0){
  int idx = blockIdx.x*256 + threadIdx.x;   // exactly 833*32*168
  int i = idx % 168;
  int r = idx / 168;       // t*32+b
  int b = r & 31;
  int t = r >> 5;
  x0[idx] = train[b*1024 + t + i] / levs[b*1024 + t + 167];
}

// ---------------- out_win -> d_out second half ----------------
__global__ void win_out_k(const float* __restrict__ train, const float* __restrict__ levs,
                          float* __restrict__ ow){
  int idx = blockIdx.x*256 + threadIdx.x;   // exactly 833*32*24
  int o = idx % 24;
  int r = idx / 24;
  int b = r & 31;
  int t = r >> 5;
  ow[idx] = train[b*1024 + 168 + t + o] / levs[b*1024 + t + 167];
}

// ---------------- pack whh[1024][256] fp32 -> wp[k4][512] uint4 of 8 halves ----------------
// wp[k4][t] = {w[t][4k4..4k4+3], w[t+512][4k4..4k4+3]} as fp16.
__global__ void pack_k(const float* __restrict__ w, uint4* __restrict__ wp){
  int idx = blockIdx.x*256 + threadIdx.x;   // 32768
  int t = idx & 511, k4 = idx >> 9;
  float4 a = *reinterpret_cast<const float4*>(w + (size_t)t*256 + k4*4);
  float4 b = *reinterpret_cast<const float4*>(w + (size_t)(t+512)*256 + k4*4);
  union { uint4 u; __half h[8]; } r;
  r.h[0]=__float2half(a.x); r.h[1]=__float2half(a.y); r.h[2]=__float2half(a.z); r.h[3]=__float2half(a.w);
  r.h[4]=__float2half(b.x); r.h[5]=__float2half(b.y); r.h[6]=__float2half(b.z); r.h[7]=__float2half(b.w);
  wp[(size_t)k4*512 + t] = r.u;
}

// ---------------- generic fp32 GEMM: C[m][n] = A[map(m)][:K] . W[n][:K] + b1 (+b2), opt tanh
__global__ __launch_bounds__(256) void proj_gemm(
    const float* __restrict__ A, const float* __restrict__ W,
    const float* __restrict__ b1, const float* __restrict__ b2,
    float* __restrict__ C, int Mout, int K, int N, int dil, int act)
{
  __shared__ float As[16][68];
  __shared__ float Bs[16][68];
  int tid = threadIdx.x;
  int tx = tid & 15, ty = tid >> 4;
  int m0 = blockIdx.y << 6, n0 = blockIdx.x << 6;
  int amap[4];
  #pragma unroll
  for (int i = 0; i < 4; ++i){
    int m = m0 + (tid >> 4) + i*16;
    int row;
    if (dil == 0){ row = (m < Mout) ? m : -1; }
    else {
      int rows = dil << 5;
      int j = m / rows;
      int q = m - j*rows;
      int t = j*dil + (q >> 5);
      row = (t < TT) ? ((t << 5) + (q & 31)) : -1;
    }
    amap[i] = row;
  }
  float acc[4][4] = {{0.f,0.f,0.f,0.f},{0.f,0.f,0.f,0.f},{0.f,0.f,0.f,0.f},{0.f,0.f,0.f,0.f}};
  int nkt = (K + 15) >> 4;
  for (int kt = 0; kt < nkt; ++kt){
    int kk = (kt << 4) + (tid & 15);
    bool kin = kk < K;
    #pragma unroll
    for (int i = 0; i < 4; ++i){
      int ml = (tid >> 4) + i*16;
      As[tid & 15][ml] = (kin && amap[i] >= 0) ? A[(size_t)amap[i]*K + kk] : 0.f;
      Bs[tid & 15][ml] = kin ? W[(size_t)(n0 + ml)*K + kk] : 0.f;
    }
    __syncthreads();
    #pragma unroll
    for (int k = 0; k < 16; ++k){
      float4 av = *reinterpret_cast<const float4*>(&As[k][ty << 2]);
      float4 bv = *reinterpret_cast<const float4*>(&Bs[k][tx << 2]);
      float a4[4] = {av.x, av.y, av.z, av.w};
      float b4[4] = {bv.x, bv.y, bv.z, bv.w};
      #pragma unroll
      for (int i = 0; i < 4; ++i)
        #pragma unroll
        for (int j = 0; j < 4; ++j)
          acc[i][j] = fmaf(a4[i], b4[j], acc[i][j]);
    }
    __syncthreads();
  }
  #pragma unroll
  for (int i = 0; i < 4; ++i){
    int m = m0 + (ty << 2) + i;
    if (m >= Mout) continue;
    #pragma unroll
    for (int j = 0; j < 4; ++j){
      int n = n0 + (tx << 2) + j;
      float v = acc[i][j] + b1[n] + (b2 ? b2[n] : 0.f);
      if (act) v = tanhf(v);
      C[(size_t)m*N + n] = v;
    }
  }
}

// ---------------- CU-resident-weight dilated-LSTM recurrence ----------------
// One WG owns NR whole rows; zero cross-WG traffic. 64 weight slabs (8KB each):
//   [0,WREG)           -> VGPR-pinned. HARD LESSON (r5/r6): this kernel gets a
//                         128-VGPR allocation; WREG*4 + ~45 live must stay < 128
//                         or the array spills into the step loop (~1GB scratch HBM
//                         traffic + L2 thrash). Keep WREG <= 12 (NR<=2), 8 (NR=8).
//   [WREG,WREG+WLDS)   -> LDS
//   rest               -> streamed from L2 each step (44.8 B/cy/CU measured r4)
// h[256]/row + c in LDS fp32. Thread t owns gate rows t, t+512.
template<int NR, int WREG, int WLDS>
__global__ __launch_bounds__(512) void srec_k(
    const uint4* __restrict__ wp, const float* __restrict__ Gin,
    float* __restrict__ out, const float* __restrict__ res,
    int nsteps, int d, int rowsTotal)
{
  constexpr int NSTREAM = 64 - WREG - WLDS;
  extern __shared__ char smc[];
  uint4*  wlds = reinterpret_cast<uint4*>(smc);                       // [WLDS*512]
  float4* hh   = reinterpret_cast<float4*>(smc + WLDS*8192);          // [NR][64]
  float*  psum = reinterpret_cast<float*>(smc + WLDS*8192 + NR*1024); // [NR][1024]
  float*  cst  = reinterpret_cast<float*>(smc + WLDS*8192 + NR*1024 + NR*4096); // [NR][256]
  const int tid = threadIdx.x;
  const int q0 = blockIdx.x*NR;

  uint4 wreg[WREG];
  #pragma unroll
  for (int k = 0; k < WREG; ++k) wreg[k] = wp[(size_t)k*512 + tid];
  for (int e = tid; e < WLDS*512; e += 512) wlds[e] = wp[(size_t)WREG*512 + e];
  for (int e = tid; e < NR*64; e += 512) hh[e] = make_float4(0.f,0.f,0.f,0.f);
  for (int e = tid; e < NR*256; e += 512) cst[e] = 0.f;
  __syncthreads();

  for (int step = 0; step < nsteps; ++step){
    float ginA[NR], ginB[NR];
    const float* gbase = Gin + ((size_t)step*rowsTotal + q0)*GDIM;
    #pragma unroll
    for (int rr = 0; rr < NR; ++rr){
      ginA[rr] = gbase[rr*GDIM + tid];
      ginB[rr] = gbase[rr*GDIM + tid + 512];
    }
    float accA0[NR], accA1[NR], accB0[NR], accB1[NR];
    #pragma unroll
    for (int rr = 0; rr < NR; ++rr){ accA0[rr]=0.f; accA1[rr]=0.f; accB0[rr]=0.f; accB1[rr]=0.f; }

#define SLAB_BODY(WVAL, K4)                                              \
    {                                                                    \
      union { uint4 u; __half2 h2[4]; } wu_; wu_.u = (WVAL);             \
      float w0 = __half2float(__low2half(wu_.h2[0]));                    \
      float w1 = __half2float(__high2half(wu_.h2[0]));                   \
      float w2 = __half2float(__low2half(wu_.h2[1]));                    \
      float w3 = __half2float(__high2half(wu_.h2[1]));                   \
      float w4 = __half2float(__low2half(wu_.h2[2]));                    \
      float w5 = __half2float(__high2half(wu_.h2[2]));                   \
      float w6 = __half2float(__low2half(wu_.h2[3]));                    \
      float w7 = __half2float(__high2half(wu_.h2[3]));                   \
      _Pragma("unroll")                                                  \
      for (int rr = 0; rr < NR; ++rr){                                   \
        float4 h4 = hh[rr*64 + (K4)];                                    \
        accA0[rr] = fmaf(w0, h4.x, accA0[rr]);                           \
        accA1[rr] = fmaf(w1, h4.y, accA1[rr]);                           \
        accA0[rr] = fmaf(w2, h4.z, accA0[rr]);                           \
        accA1[rr] = fmaf(w3, h4.w, accA1[rr]);                           \
        accB0[rr] = fmaf(w4, h4.x, accB0[rr]);                           \
        accB1[rr] = fmaf(w5, h4.y, accB1[rr]);                           \
        accB0[rr] = fmaf(w6, h4.z, accB0[rr]);                           \
        accB1[rr] = fmaf(w7, h4.w, accB1[rr]);                           \
      }                                                                  \
    }

    #pragma unroll
    for (int k4 = 0; k4 < WREG; ++k4) SLAB_BODY(wreg[k4], k4)
    #pragma unroll
    for (int j = 0; j < WLDS; ++j) SLAB_BODY(wlds[j*512 + tid], WREG + j)
    #pragma unroll
    for (int j = 0; j < NSTREAM; ++j)
      SLAB_BODY(wp[(size_t)(WREG + WLDS + j)*512 + tid], WREG + WLDS + j)
#undef SLAB_BODY

    #pragma unroll
    for (int rr = 0; rr < NR; ++rr){
      psum[rr*1024 + tid]       = accA0[rr] + accA1[rr] + ginA[rr];
      psum[rr*1024 + tid + 512] = accB0[rr] + accB1[rr] + ginB[rr];
    }
    __syncthreads();
    if (tid < 256){
      #pragma unroll
      for (int rr = 0; rr < NR; ++rr){
        float iv = psum[rr*1024 + tid];
        float fv = psum[rr*1024 + tid + 256];
        float gv = psum[rr*1024 + tid + 512];
        float ov = psum[rr*1024 + tid + 768];
        float c = cst[rr*256 + tid];
        c = sigm(fv)*c + sigm(iv)*tanhf(gv);
        float h = sigm(ov)*tanhf(c);
        cst[rr*256 + tid] = c;
        reinterpret_cast<float*>(hh + rr*64)[tid] = h;
        int q = q0 + rr;
        int tg = step*d + (q >> 5);
        if (tg < TT){
          size_t oi = ((size_t)tg*32 + (q & 31))*256 + tid;
          out[oi] = res ? (h + res[oi]) : h;
        }
      }
    }
    __syncthreads();
  }
}

// ---------------- scoring head: pred[m][24] = xt[m][:] . sc_w[n][:] + sc_b ----------------
__global__ __launch_bounds__(256) void sc_head(const float* __restrict__ xt, const float* __restrict__ w,
                        const float* __restrict__ bias, float* __restrict__ outp, int M){
  __shared__ float arow[8][256];
  int m0 = blockIdx.x << 3;
  int tid = threadIdx.x;
  #pragma unroll
  for (int i = 0; i < 8; ++i){
    int e = tid + (i << 8);
    int r = e >> 8, k = e & 255;
    arow[r][k] = (m0 + r < M) ? xt[(size_t)(m0 + r)*256 + k] : 0.f;
  }
  __syncthreads();
  int r = tid >> 5, n = tid & 31;
  if (n < 24 && (m0 + r) < M){
    float acc = bias[n];
    const float* wr = w + n*256;
    #pragma unroll 8
    for (int k = 0; k < 256; ++k) acc = fmaf(arow[r][k], wr[k], acc);
    outp[(size_t)(m0 + r)*24 + n] = acc;
  }
}

extern "C" void kernel_launch(void* const* d_in, const int* in_sizes, int n_in,
                              void* d_out, int out_size, void* d_ws, size_t ws_size,
                              hipStream_t stream){
  const float* train = (const float*)d_in[0];
  const float* ism   = (const float*)d_in[4];
  const float* wih[4] = {(const float*)d_in[5], (const float*)d_in[9], (const float*)d_in[13], (const float*)d_in[17]};
  const float* whh[4] = {(const float*)d_in[6], (const float*)d_in[10], (const float*)d_in[14], (const float*)d_in[18]};
  const float* bih[4] = {(const float*)d_in[7], (const float*)d_in[11], (const float*)d_in[15], (const float*)d_in[19]};
  const float* bhh[4] = {(const float*)d_in[8], (const float*)d_in[12], (const float*)d_in[16], (const float*)d_in[20]};
  const float* nl_w = (const float*)d_in[21];
  const float* nl_b = (const float*)d_in[22];
  const float* sc_w = (const float*)d_in[23];
  const float* sc_b = (const float*)d_in[24];
  float* out = (float*)d_out;

  float* ws = (float*)d_ws;
  size_t off = 0;
  float* levs = ws + off;   off += 32768;
  uint4* wpk[4];
  for (int l = 0; l < 4; ++l){ wpk[l] = (uint4*)(ws + off); off += 131072; }  // 512KB each
  float* x0 = ws + off;     off += (size_t)26656*168;
  float* G  = ws + off;     off += (size_t)28672*1024;
  float* h0 = ws + off;     off += (size_t)26656*256;
  float* h1 = ws + off;     off += (size_t)26656*256;
  float* h2 = ws + off;     off += (size_t)26656*256;
  (void)ws_size; (void)in_sizes; (void)n_in; (void)out_size;

  levels_k<<<1, 64, 0, stream>>>(train, ism, levs);
  win_x_k<<<17493, 256, 0, stream>>>(train, levs, x0);
  win_out_k<<<2499, 256, 0, stream>>>(train, levs, out + 639744);
  for (int l = 0; l < 4; ++l)
    pack_k<<<128, 256, 0, stream>>>(whh[l], wpk[l]);

  // dynamic-LDS sizes: WLDS*8192 + NR*6144 (<= 163840)
  const int SM1 = 19*8192 + 1*6144;    // 161792
  const int SM2 = 18*8192 + 2*6144;    // 159744
  const int SM8 = 13*8192 + 8*6144;    // 155648
  hipFuncSetAttribute(reinterpret_cast<const void*>(&srec_k<1,12,19>),
                      hipFuncAttributeMaxDynamicSharedMemorySize, SM1);
  hipFuncSetAttribute(reinterpret_cast<const void*>(&srec_k<2,12,18>),
                      hipFuncAttributeMaxDynamicSharedMemorySize, SM2);
  hipFuncSetAttribute(reinterpret_cast<const void*>(&srec_k<8,8,13>),
                      hipFuncAttributeMaxDynamicSharedMemorySize, SM8);

  // layer 0 (d=1): 833 steps, 32 rows -> 32 WGs x 1 row
  proj_gemm<<<dim3(16,417), 256, 0, stream>>>(x0, wih[0], bih[0], bhh[0], G, 26656, 168, 1024, 0, 0);
  srec_k<1,12,19><<<32, 512, SM1, stream>>>(wpk[0], G, h0, nullptr, 833, 1, 32);
  // layer 1 (d=4): 209 steps, 128 rows -> 128 WGs x 1 row
  proj_gemm<<<dim3(16,418), 256, 0, stream>>>(h0, wih[1], bih[1], bhh[1], G, 26752, 256, 1024, 4, 0);
  srec_k<1,12,19><<<128, 512, SM1, stream>>>(wpk[1], G, h1, nullptr, 209, 4, 128);
  // layer 2 (d=16): 53 steps, 512 rows -> 256 WGs x 2 rows
  proj_gemm<<<dim3(16,424), 256, 0, stream>>>(h1, wih[2], bih[2], bhh[2], G, 27136, 256, 1024, 16, 0);
  srec_k<2,12,18><<<256, 512, SM2, stream>>>(wpk[2], G, h2, nullptr, 53, 16, 512);
  // layer 3 (d=64): 14 steps, 2048 rows -> 256 WGs x 8 rows; residual h1; out overwrites h2
  proj_gemm<<<dim3(16,448), 256, 0, stream>>>(h2, wih[3], bih[3], bhh[3], G, 28672, 256, 1024, 64, 0);
  srec_k<8,8,13><<<256, 512, SM8, stream>>>(wpk[3], G, h2, h1, 14, 64, 2048);
  // nonlinear dense: xt = tanh(xf @ nl_w.T + nl_b)  (reuse h0)
  proj_gemm<<<dim3(4,417), 256, 0, stream>>>(h2, nl_w, nl_b, nullptr, h0, 26656, 256, 256, 0, 1);
  // scoring head -> pred (first half of d_out)
  sc_head<<<3332, 256, 0, stream>>>(h0, sc_w, sc_b, out, 26656);
}

// Round 8
// 6516.336 us; speedup vs baseline: 2.8261x; 2.8261x over previous
//
#include <hip/hip_runtime.h>
#include <hip/hip_fp16.h>
#include <math.h>

#define TT 833          // output timesteps
#define GDIM 1024       // 4*H gates

__device__ __forceinline__ float sigm(float x){ return 1.f/(1.f+expf(-x)); }

// ---------------- level smoothing scan ----------------
__global__ void levels_k(const float* __restrict__ train, const float* __restrict__ ism,
                         float* __restrict__ levs){
  int b = threadIdx.x;
  if (b >= 32) return;
  float a = 1.f/(1.f+expf(-ism[0]));
  const float* tr = train + b*1024;
  float* lv = levs + b*1024;
  float lev = fmaxf(tr[0], 0.1f);
  lv[0] = lev;
  for (int t = 1; t < 1024; ++t){
    lev = fmaxf(a*tr[t] + (1.f-a)*lev, 0.1f);
    lv[t] = lev;
  }
}

// ---------------- normalized input windows x0[t*32+b][168] ----------------
__global__ void win_x_k(const float* __restrict__ train, const float* __restrict__ levs,
                        float* __restrict__ x0){
  int idx = blockIdx.x*256 + threadIdx.x;   // exactly 833*32*168
  int i = idx % 168;
  int r = idx / 168;       // t*32+b
  int b = r & 31;
  int t = r >> 5;
  x0[idx] = train[b*1024 + t + i] / levs[b*1024 + t + 167];
}

// ---------------- out_win -> d_out second half ----------------
__global__ void win_out_k(const float* __restrict__ train, const float* __restrict__ levs,
                          float* __restrict__ ow){
  int idx = blockIdx.x*256 + threadIdx.x;   // exactly 833*32*24
  int o = idx % 24;
  int r = idx / 24;
  int b = r & 31;
  int t = r >> 5;
  ow[idx] = train[b*1024 + 168 + t + o] / levs[b*1024 + t + 167];
}

// ---------------- pack whh[1024][256] fp32 -> wp8[k8][1024] uint4 of 8 halves ----------------
// wp8[k8][g] = w[g][8*k8 .. 8*k8+8) as fp16. One gate row per thread in srec8_k.
__global__ void pack8_k(const float* __restrict__ w, uint4* __restrict__ wp){
  int idx = blockIdx.x*256 + threadIdx.x;   // 32768
  int g = idx & 1023, k8 = idx >> 10;
  float4 a = *reinterpret_cast<const float4*>(w + (size_t)g*256 + k8*8);
  float4 b = *reinterpret_cast<const float4*>(w + (size_t)g*256 + k8*8 + 4);
  union { uint4 u; __half h[8]; } r;
  r.h[0]=__float2half(a.x); r.h[1]=__float2half(a.y); r.h[2]=__float2half(a.z); r.h[3]=__float2half(a.w);
  r.h[4]=__float2half(b.x); r.h[5]=__float2half(b.y); r.h[6]=__float2half(b.z); r.h[7]=__float2half(b.w);
  wp[(size_t)k8*1024 + g] = r.u;
}

// ---------------- generic fp32 GEMM: C[m][n] = A[map(m)][:K] . W[n][:K] + b1 (+b2), opt tanh
__global__ __launch_bounds__(256) void proj_gemm(
    const float* __restrict__ A, const float* __restrict__ W,
    const float* __restrict__ b1, const float* __restrict__ b2,
    float* __restrict__ C, int Mout, int K, int N, int dil, int act)
{
  __shared__ float As[16][68];
  __shared__ float Bs[16][68];
  int tid = threadIdx.x;
  int tx = tid & 15, ty = tid >> 4;
  int m0 = blockIdx.y << 6, n0 = blockIdx.x << 6;
  int amap[4];
  #pragma unroll
  for (int i = 0; i < 4; ++i){
    int m = m0 + (tid >> 4) + i*16;
    int row;
    if (dil == 0){ row = (m < Mout) ? m : -1; }
    else {
      int rows = dil << 5;
      int j = m / rows;
      int q = m - j*rows;
      int t = j*dil + (q >> 5);
      row = (t < TT) ? ((t << 5) + (q & 31)) : -1;
    }
    amap[i] = row;
  }
  float acc[4][4] = {{0.f,0.f,0.f,0.f},{0.f,0.f,0.f,0.f},{0.f,0.f,0.f,0.f},{0.f,0.f,0.f,0.f}};
  int nkt = (K + 15) >> 4;
  for (int kt = 0; kt < nkt; ++kt){
    int kk = (kt << 4) + (tid & 15);
    bool kin = kk < K;
    #pragma unroll
    for (int i = 0; i < 4; ++i){
      int ml = (tid >> 4) + i*16;
      As[tid & 15][ml] = (kin && amap[i] >= 0) ? A[(size_t)amap[i]*K + kk] : 0.f;
      Bs[tid & 15][ml] = kin ? W[(size_t)(n0 + ml)*K + kk] : 0.f;
    }
    __syncthreads();
    #pragma unroll
    for (int k = 0; k < 16; ++k){
      float4 av = *reinterpret_cast<const float4*>(&As[k][ty << 2]);
      float4 bv = *reinterpret_cast<const float4*>(&Bs[k][tx << 2]);
      float a4[4] = {av.x, av.y, av.z, av.w};
      float b4[4] = {bv.x, bv.y, bv.z, bv.w};
      #pragma unroll
      for (int i = 0; i < 4; ++i)
        #pragma unroll
        for (int j = 0; j < 4; ++j)
          acc[i][j] = fmaf(a4[i], b4[j], acc[i][j]);
    }
    __syncthreads();
  }
  #pragma unroll
  for (int i = 0; i < 4; ++i){
    int m = m0 + (ty << 2) + i;
    if (m >= Mout) continue;
    #pragma unroll
    for (int j = 0; j < 4; ++j){
      int n = n0 + (tx << 2) + j;
      float v = acc[i][j] + b1[n] + (b2 ? b2[n] : 0.f);
      if (act) v = tanhf(v);
      C[(size_t)m*N + n] = v;
    }
  }
}

// ---------------- streamed-weight dilated-LSTM recurrence, 1024 threads ----------------
// One WG owns NR whole rows (independent recurrences); zero cross-WG traffic.
// Round-4 structure (known good: pure streaming, rolled loop, small LDS) with 2x waves
// for 2x memory-level parallelism. Thread t owns gate row t for all NR rows.
// Weights streamed from L2 every step: 32 x uint4 (16B/lane coalesced) = 512KB/WG/step.
// NO reg/LDS pinning (r5-r7 lesson: every pinning variant ran ~3x slower than streaming).
// Gates: i=[0,256) f=[256,512) g=[512,768) o=[768,1024).
template<int NR>
__global__ __launch_bounds__(1024) void srec8_k(
    const uint4* __restrict__ wp8, const float* __restrict__ Gin,
    float* __restrict__ out, const float* __restrict__ res,
    int nsteps, int d, int rowsTotal)
{
  __shared__ float4 hh[NR][64];      // h[256] per row as float4
  __shared__ float psum[NR][1024];
  __shared__ float cst[NR][256];
  const int tid = threadIdx.x;
  const int q0 = blockIdx.x*NR;
  for (int e = tid; e < NR*64; e += 1024) (&hh[0][0])[e] = make_float4(0.f,0.f,0.f,0.f);
  for (int e = tid; e < NR*256; e += 1024) (&cst[0][0])[e] = 0.f;
  __syncthreads();

  for (int step = 0; step < nsteps; ++step){
    float gin[NR];
    const float* gbase = Gin + ((size_t)step*rowsTotal + q0)*GDIM;
    #pragma unroll
    for (int rr = 0; rr < NR; ++rr) gin[rr] = gbase[rr*GDIM + tid];
    float acc[NR];
    #pragma unroll
    for (int rr = 0; rr < NR; ++rr) acc[rr] = 0.f;

    #pragma unroll 4
    for (int k8 = 0; k8 < 32; ++k8){
      uint4 w = wp8[(size_t)k8*1024 + tid];
      union { unsigned u; __half2 h2; } c0, c1, c2, c3;
      c0.u = w.x; c1.u = w.y; c2.u = w.z; c3.u = w.w;
      float w0 = __half2float(__low2half(c0.h2)), w1 = __half2float(__high2half(c0.h2));
      float w2 = __half2float(__low2half(c1.h2)), w3 = __half2float(__high2half(c1.h2));
      float w4 = __half2float(__low2half(c2.h2)), w5 = __half2float(__high2half(c2.h2));
      float w6 = __half2float(__low2half(c3.h2)), w7 = __half2float(__high2half(c3.h2));
      #pragma unroll
      for (int rr = 0; rr < NR; ++rr){
        float4 ha = hh[rr][2*k8];
        float4 hb = hh[rr][2*k8 + 1];
        acc[rr] = fmaf(w0, ha.x, acc[rr]);
        acc[rr] = fmaf(w1, ha.y, acc[rr]);
        acc[rr] = fmaf(w2, ha.z, acc[rr]);
        acc[rr] = fmaf(w3, ha.w, acc[rr]);
        acc[rr] = fmaf(w4, hb.x, acc[rr]);
        acc[rr] = fmaf(w5, hb.y, acc[rr]);
        acc[rr] = fmaf(w6, hb.z, acc[rr]);
        acc[rr] = fmaf(w7, hb.w, acc[rr]);
      }
    }
    #pragma unroll
    for (int rr = 0; rr < NR; ++rr) psum[rr][tid] = acc[rr] + gin[rr];
    __syncthreads();
    for (int e = tid; e < NR*256; e += 1024){
      int rr = e >> 8, j = e & 255;
      float iv = psum[rr][j];
      float fv = psum[rr][j + 256];
      float gv = psum[rr][j + 512];
      float ov = psum[rr][j + 768];
      float c = cst[rr][j];
      c = sigm(fv)*c + sigm(iv)*tanhf(gv);
      float h = sigm(ov)*tanhf(c);
      cst[rr][j] = c;
      reinterpret_cast<float*>(&hh[rr][0])[j] = h;
      int q = q0 + rr;
      int tg = step*d + (q >> 5);
      if (tg < TT){
        size_t oi = ((size_t)tg*32 + (q & 31))*256 + j;
        out[oi] = res ? (h + res[oi]) : h;
      }
    }
    __syncthreads();
  }
}

// ---------------- scoring head: pred[m][24] = xt[m][:] . sc_w[n][:] + sc_b ----------------
__global__ __launch_bounds__(256) void sc_head(const float* __restrict__ xt, const float* __restrict__ w,
                        const float* __restrict__ bias, float* __restrict__ outp, int M){
  __shared__ float arow[8][256];
  int m0 = blockIdx.x << 3;
  int tid = threadIdx.x;
  #pragma unroll
  for (int i = 0; i < 8; ++i){
    int e = tid + (i << 8);
    int r = e >> 8, k = e & 255;
    arow[r][k] = (m0 + r < M) ? xt[(size_t)(m0 + r)*256 + k] : 0.f;
  }
  __syncthreads();
  int r = tid >> 5, n = tid & 31;
  if (n < 24 && (m0 + r) < M){
    float acc = bias[n];
    const float* wr = w + n*256;
    #pragma unroll 8
    for (int k = 0; k < 256; ++k) acc = fmaf(arow[r][k], wr[k], acc);
    outp[(size_t)(m0 + r)*24 + n] = acc;
  }
}

extern "C" void kernel_launch(void* const* d_in, const int* in_sizes, int n_in,
                              void* d_out, int out_size, void* d_ws, size_t ws_size,
                              hipStream_t stream){
  const float* train = (const float*)d_in[0];
  const float* ism   = (const float*)d_in[4];
  const float* wih[4] = {(const float*)d_in[5], (const float*)d_in[9], (const float*)d_in[13], (const float*)d_in[17]};
  const float* whh[4] = {(const float*)d_in[6], (const float*)d_in[10], (const float*)d_in[14], (const float*)d_in[18]};
  const float* bih[4] = {(const float*)d_in[7], (const float*)d_in[11], (const float*)d_in[15], (const float*)d_in[19]};
  const float* bhh[4] = {(const float*)d_in[8], (const float*)d_in[12], (const float*)d_in[16], (const float*)d_in[20]};
  const float* nl_w = (const float*)d_in[21];
  const float* nl_b = (const float*)d_in[22];
  const float* sc_w = (const float*)d_in[23];
  const float* sc_b = (const float*)d_in[24];
  float* out = (float*)d_out;

  float* ws = (float*)d_ws;
  size_t off = 0;
  float* levs = ws + off;   off += 32768;
  uint4* wpk[4];
  for (int l = 0; l < 4; ++l){ wpk[l] = (uint4*)(ws + off); off += 131072; }  // 512KB each
  float* x0 = ws + off;     off += (size_t)26656*168;
  float* G  = ws + off;     off += (size_t)28672*1024;
  float* h0 = ws + off;     off += (size_t)26656*256;
  float* h1 = ws + off;     off += (size_t)26656*256;
  float* h2 = ws + off;     off += (size_t)26656*256;
  (void)ws_size; (void)in_sizes; (void)n_in; (void)out_size;

  levels_k<<<1, 64, 0, stream>>>(train, ism, levs);
  win_x_k<<<17493, 256, 0, stream>>>(train, levs, x0);
  win_out_k<<<2499, 256, 0, stream>>>(train, levs, out + 639744);
  for (int l = 0; l < 4; ++l)
    pack8_k<<<128, 256, 0, stream>>>(whh[l], wpk[l]);

  // layer 0 (d=1): 833 steps, 32 rows -> 32 WGs x 1 row
  proj_gemm<<<dim3(16,417), 256, 0, stream>>>(x0, wih[0], bih[0], bhh[0], G, 26656, 168, 1024, 0, 0);
  srec8_k<1><<<32, 1024, 0, stream>>>(wpk[0], G, h0, nullptr, 833, 1, 32);
  // layer 1 (d=4): 209 steps, 128 rows -> 128 WGs x 1 row
  proj_gemm<<<dim3(16,418), 256, 0, stream>>>(h0, wih[1], bih[1], bhh[1], G, 26752, 256, 1024, 4, 0);
  srec8_k<1><<<128, 1024, 0, stream>>>(wpk[1], G, h1, nullptr, 209, 4, 128);
  // layer 2 (d=16): 53 steps, 512 rows -> 256 WGs x 2 rows
  proj_gemm<<<dim3(16,424), 256, 0, stream>>>(h1, wih[2], bih[2], bhh[2], G, 27136, 256, 1024, 16, 0);
  srec8_k<2><<<256, 1024, 0, stream>>>(wpk[2], G, h2, nullptr, 53, 16, 512);
  // layer 3 (d=64): 14 steps, 2048 rows -> 256 WGs x 8 rows; residual h1; out overwrites h2
  proj_gemm<<<dim3(16,448), 256, 0, stream>>>(h2, wih[3], bih[3], bhh[3], G, 28672, 256, 1024, 64, 0);
  srec8_k<8><<<256, 1024, 0, stream>>>(wpk[3], G, h2, h1, 14, 64, 2048);
  // nonlinear dense: xt = tanh(xf @ nl_w.T + nl_b)  (reuse h0)
  proj_gemm<<<dim3(4,417), 256, 0, stream>>>(h2, nl_w, nl_b, nullptr, h0, 26656, 256, 256, 0, 1);
  // scoring head -> pred (first half of d_out)
  sc_head<<<3332, 256, 0, stream>>>(h0, sc_w, sc_b, out, 26656);
}

// Round 9
// 5998.010 us; speedup vs baseline: 3.0703x; 1.0864x over previous
//
#include <hip/hip_runtime.h>
#include <hip/hip_fp16.h>
#include <math.h>

#define TT 833          // output timesteps
#define GDIM 1024       // 4*H gates

typedef _Float16 f16x8 __attribute__((ext_vector_type(8)));
typedef float    f32x4 __attribute__((ext_vector_type(4)));

__device__ __forceinline__ float sigm(float x){ return 1.f/(1.f+expf(-x)); }

// ---------------- level smoothing scan ----------------
__global__ void levels_k(const float* __restrict__ train, const float* __restrict__ ism,
                         float* __restrict__ levs){
  int b = threadIdx.x;
  if (b >= 32) return;
  float a = 1.f/(1.f+expf(-ism[0]));
  const float* tr = train + b*1024;
  float* lv = levs + b*1024;
  float lev = fmaxf(tr[0], 0.1f);
  lv[0] = lev;
  for (int t = 1; t < 1024; ++t){
    lev = fmaxf(a*tr[t] + (1.f-a)*lev, 0.1f);
    lv[t] = lev;
  }
}

// ---------------- normalized input windows x0[t*32+b][168] ----------------
__global__ void win_x_k(const float* __restrict__ train, const float* __restrict__ levs,
                        float* __restrict__ x0){
  int idx = blockIdx.x*256 + threadIdx.x;   // exactly 833*32*168
  int i = idx % 168;
  int r = idx / 168;       // t*32+b
  int b = r & 31;
  int t = r >> 5;
  x0[idx] = train[b*1024 + t + i] / levs[b*1024 + t + 167];
}

// ---------------- out_win -> d_out second half ----------------
__global__ void win_out_k(const float* __restrict__ train, const float* __restrict__ levs,
                          float* __restrict__ ow){
  int idx = blockIdx.x*256 + threadIdx.x;   // exactly 833*32*24
  int o = idx % 24;
  int r = idx / 24;
  int b = r & 31;
  int t = r >> 5;
  ow[idx] = train[b*1024 + 168 + t + o] / levs[b*1024 + t + 167];
}

// ---------------- pack whh[1024][256] fp32 -> wp8[k8][1024] uint4 of 8 halves ----------------
__global__ void pack8_k(const float* __restrict__ w, uint4* __restrict__ wp){
  int idx = blockIdx.x*256 + threadIdx.x;   // 32768
  int g = idx & 1023, k8 = idx >> 10;
  float4 a = *reinterpret_cast<const float4*>(w + (size_t)g*256 + k8*8);
  float4 b = *reinterpret_cast<const float4*>(w + (size_t)g*256 + k8*8 + 4);
  union { uint4 u; __half h[8]; } r;
  r.h[0]=__float2half(a.x); r.h[1]=__float2half(a.y); r.h[2]=__float2half(a.z); r.h[3]=__float2half(a.w);
  r.h[4]=__float2half(b.x); r.h[5]=__float2half(b.y); r.h[6]=__float2half(b.z); r.h[7]=__float2half(b.w);
  wp[(size_t)k8*1024 + g] = r.u;
}

// ---------------- MFMA fp16 GEMM: C[m][n] = A[map(m)][:K] . W[n][:K] + b1 (+b2), opt tanh ----
// 128x128 tile, 4 waves (2x2), mfma_f32_16x16x32_f16, 4x4 frags/wave, BK=32.
// A,W fp32 in memory -> fp16 in LDS (stride 40 halves = 80B, 16B-aligned rows).
// dil!=0 applies the dilated-reshape row remap; out-of-range rows read as zero.
__global__ __launch_bounds__(256) void proj_mfma(
    const float* __restrict__ A, const float* __restrict__ W,
    const float* __restrict__ b1, const float* __restrict__ b2,
    float* __restrict__ C, int Mout, int K, int N, int dil, int act)
{
  __shared__ _Float16 As[128*40];
  __shared__ _Float16 Bs[128*40];
  const int tid = threadIdx.x;
  const int lane = tid & 63;
  const int w = tid >> 6, wr = w >> 1, wc = w & 1;
  const int m0 = blockIdx.y << 7, n0 = blockIdx.x << 7;

  // source row for the A-tile row this thread stages (2 threads per row)
  const int rowA = tid >> 1;
  int srcrow;
  {
    int m = m0 + rowA;
    if (dil == 0) srcrow = (m < Mout) ? m : -1;
    else {
      int rows = dil << 5;
      int j = m / rows;
      int q = m - j*rows;
      int t = j*dil + (q >> 5);
      srcrow = (t < TT) ? ((t << 5) + (q & 31)) : -1;
    }
  }
  const int halfsel = tid & 1;            // which 16-k chunk of the 32-k slab
  const int nrow = n0 + rowA;             // W row staged by this thread (always < N)

  f32x4 acc[4][4];
  #pragma unroll
  for (int i = 0; i < 4; ++i)
    #pragma unroll
    for (int j = 0; j < 4; ++j) acc[i][j] = (f32x4){0.f,0.f,0.f,0.f};

  const int nkt = (K + 31) >> 5;
  for (int kt = 0; kt < nkt; ++kt){
    const int k0 = (kt << 5) + halfsel*16;
    // ---- stage A (16 fp32 -> fp16) ----
    {
      union { uint4 u[2]; _Float16 h[16]; } tmp;
      if (srcrow >= 0 && k0 + 16 <= K){
        const float* s = A + (size_t)srcrow*K + k0;
        #pragma unroll
        for (int j = 0; j < 4; ++j){
          float4 v = *reinterpret_cast<const float4*>(s + j*4);
          tmp.h[j*4+0]=(_Float16)v.x; tmp.h[j*4+1]=(_Float16)v.y;
          tmp.h[j*4+2]=(_Float16)v.z; tmp.h[j*4+3]=(_Float16)v.w;
        }
      } else {
        const float* s = (srcrow >= 0) ? A + (size_t)srcrow*K : nullptr;
        #pragma unroll
        for (int j = 0; j < 16; ++j){
          int kk = k0 + j;
          tmp.h[j] = (s && kk < K) ? (_Float16)s[kk] : (_Float16)0.f;
        }
      }
      uint4* dst = reinterpret_cast<uint4*>(&As[rowA*40 + halfsel*16]);
      dst[0] = tmp.u[0]; dst[1] = tmp.u[1];
    }
    // ---- stage B (W row nrow) ----
    {
      union { uint4 u[2]; _Float16 h[16]; } tmp;
      if (k0 + 16 <= K){
        const float* s = W + (size_t)nrow*K + k0;
        #pragma unroll
        for (int j = 0; j < 4; ++j){
          float4 v = *reinterpret_cast<const float4*>(s + j*4);
          tmp.h[j*4+0]=(_Float16)v.x; tmp.h[j*4+1]=(_Float16)v.y;
          tmp.h[j*4+2]=(_Float16)v.z; tmp.h[j*4+3]=(_Float16)v.w;
        }
      } else {
        const float* s = W + (size_t)nrow*K;
        #pragma unroll
        for (int j = 0; j < 16; ++j){
          int kk = k0 + j;
          tmp.h[j] = (kk < K) ? (_Float16)s[kk] : (_Float16)0.f;
        }
      }
      uint4* dst = reinterpret_cast<uint4*>(&Bs[rowA*40 + halfsel*16]);
      dst[0] = tmp.u[0]; dst[1] = tmp.u[1];
    }
    __syncthreads();
    // ---- fragments + 16 MFMA ----
    {
      const int kg = lane >> 4, r16 = lane & 15;
      f16x8 af[4], bf[4];
      #pragma unroll
      for (int mi = 0; mi < 4; ++mi)
        af[mi] = *reinterpret_cast<const f16x8*>(&As[(wr*64 + mi*16 + r16)*40 + kg*8]);
      #pragma unroll
      for (int nj = 0; nj < 4; ++nj)
        bf[nj] = *reinterpret_cast<const f16x8*>(&Bs[(wc*64 + nj*16 + r16)*40 + kg*8]);
      #pragma unroll
      for (int mi = 0; mi < 4; ++mi)
        #pragma unroll
        for (int nj = 0; nj < 4; ++nj)
          acc[mi][nj] = __builtin_amdgcn_mfma_f32_16x16x32_f16(af[mi], bf[nj], acc[mi][nj], 0, 0, 0);
    }
    __syncthreads();
  }
  // ---- epilogue: bias (+bias2), opt tanh, fp32 store ----
  #pragma unroll
  for (int mi = 0; mi < 4; ++mi){
    #pragma unroll
    for (int p = 0; p < 4; ++p){
      int mrow = m0 + wr*64 + mi*16 + (lane >> 4)*4 + p;
      if (mrow >= Mout) continue;
      #pragma unroll
      for (int nj = 0; nj < 4; ++nj){
        int ncol = n0 + wc*64 + nj*16 + (lane & 15);
        float v = acc[mi][nj][p] + b1[ncol] + (b2 ? b2[ncol] : 0.f);
        if (act) v = tanhf(v);
        C[(size_t)mrow*N + ncol] = v;
      }
    }
  }
}

// ---------------- streamed-weight dilated-LSTM recurrence, 1024 threads ----------------
// (round-8 known-good: pure streaming, rolled loop, no pinning — see r5-r7 lessons)
template<int NR>
__global__ __launch_bounds__(1024) void srec8_k(
    const uint4* __restrict__ wp8, const float* __restrict__ Gin,
    float* __restrict__ out, const float* __restrict__ res,
    int nsteps, int d, int rowsTotal)
{
  __shared__ float4 hh[NR][64];      // h[256] per row as float4
  __shared__ float psum[NR][1024];
  __shared__ float cst[NR][256];
  const int tid = threadIdx.x;
  const int q0 = blockIdx.x*NR;
  for (int e = tid; e < NR*64; e += 1024) (&hh[0][0])[e] = make_float4(0.f,0.f,0.f,0.f);
  for (int e = tid; e < NR*256; e += 1024) (&cst[0][0])[e] = 0.f;
  __syncthreads();

  for (int step = 0; step < nsteps; ++step){
    float gin[NR];
    const float* gbase = Gin + ((size_t)step*rowsTotal + q0)*GDIM;
    #pragma unroll
    for (int rr = 0; rr < NR; ++rr) gin[rr] = gbase[rr*GDIM + tid];
    float acc[NR];
    #pragma unroll
    for (int rr = 0; rr < NR; ++rr) acc[rr] = 0.f;

    #pragma unroll 4
    for (int k8 = 0; k8 < 32; ++k8){
      uint4 w = wp8[(size_t)k8*1024 + tid];
      union { unsigned u; __half2 h2; } c0, c1, c2, c3;
      c0.u = w.x; c1.u = w.y; c2.u = w.z; c3.u = w.w;
      float w0 = __half2float(__low2half(c0.h2)), w1 = __half2float(__high2half(c0.h2));
      float w2 = __half2float(__low2half(c1.h2)), w3 = __half2float(__high2half(c1.h2));
      float w4 = __half2float(__low2half(c2.h2)), w5 = __half2float(__high2half(c2.h2));
      float w6 = __half2float(__low2half(c3.h2)), w7 = __half2float(__high2half(c3.h2));
      #pragma unroll
      for (int rr = 0; rr < NR; ++rr){
        float4 ha = hh[rr][2*k8];
        float4 hb = hh[rr][2*k8 + 1];
        acc[rr] = fmaf(w0, ha.x, acc[rr]);
        acc[rr] = fmaf(w1, ha.y, acc[rr]);
        acc[rr] = fmaf(w2, ha.z, acc[rr]);
        acc[rr] = fmaf(w3, ha.w, acc[rr]);
        acc[rr] = fmaf(w4, hb.x, acc[rr]);
        acc[rr] = fmaf(w5, hb.y, acc[rr]);
        acc[rr] = fmaf(w6, hb.z, acc[rr]);
        acc[rr] = fmaf(w7, hb.w, acc[rr]);
      }
    }
    #pragma unroll
    for (int rr = 0; rr < NR; ++rr) psum[rr][tid] = acc[rr] + gin[rr];
    __syncthreads();
    for (int e = tid; e < NR*256; e += 1024){
      int rr = e >> 8, j = e & 255;
      float iv = psum[rr][j];
      float fv = psum[rr][j + 256];
      float gv = psum[rr][j + 512];
      float ov = psum[rr][j + 768];
      float c = cst[rr][j];
      c = sigm(fv)*c + sigm(iv)*tanhf(gv);
      float h = sigm(ov)*tanhf(c);
      cst[rr][j] = c;
      reinterpret_cast<float*>(&hh[rr][0])[j] = h;
      int q = q0 + rr;
      int tg = step*d + (q >> 5);
      if (tg < TT){
        size_t oi = ((size_t)tg*32 + (q & 31))*256 + j;
        out[oi] = res ? (h + res[oi]) : h;
      }
    }
    __syncthreads();
  }
}

// ---------------- scoring head: pred[m][24] = xt[m][:] . sc_w[n][:] + sc_b ----------------
__global__ __launch_bounds__(256) void sc_head(const float* __restrict__ xt, const float* __restrict__ w,
                        const float* __restrict__ bias, float* __restrict__ outp, int M){
  __shared__ float arow[8][256];
  int m0 = blockIdx.x << 3;
  int tid = threadIdx.x;
  #pragma unroll
  for (int i = 0; i < 8; ++i){
    int e = tid + (i << 8);
    int r = e >> 8, k = e & 255;
    arow[r][k] = (m0 + r < M) ? xt[(size_t)(m0 + r)*256 + k] : 0.f;
  }
  __syncthreads();
  int r = tid >> 5, n = tid & 31;
  if (n < 24 && (m0 + r) < M){
    float acc = bias[n];
    const float* wr = w + n*256;
    #pragma unroll 8
    for (int k = 0; k < 256; ++k) acc = fmaf(arow[r][k], wr[k], acc);
    outp[(size_t)(m0 + r)*24 + n] = acc;
  }
}

extern "C" void kernel_launch(void* const* d_in, const int* in_sizes, int n_in,
                              void* d_out, int out_size, void* d_ws, size_t ws_size,
                              hipStream_t stream){
  const float* train = (const float*)d_in[0];
  const float* ism   = (const float*)d_in[4];
  const float* wih[4] = {(const float*)d_in[5], (const float*)d_in[9], (const float*)d_in[13], (const float*)d_in[17]};
  const float* whh[4] = {(const float*)d_in[6], (const float*)d_in[10], (const float*)d_in[14], (const float*)d_in[18]};
  const float* bih[4] = {(const float*)d_in[7], (const float*)d_in[11], (const float*)d_in[15], (const float*)d_in[19]};
  const float* bhh[4] = {(const float*)d_in[8], (const float*)d_in[12], (const float*)d_in[16], (const float*)d_in[20]};
  const float* nl_w = (const float*)d_in[21];
  const float* nl_b = (const float*)d_in[22];
  const float* sc_w = (const float*)d_in[23];
  const float* sc_b = (const float*)d_in[24];
  float* out = (float*)d_out;

  float* ws = (float*)d_ws;
  size_t off = 0;
  float* levs = ws + off;   off += 32768;
  uint4* wpk[4];
  for (int l = 0; l < 4; ++l){ wpk[l] = (uint4*)(ws + off); off += 131072; }  // 512KB each
  float* x0 = ws + off;     off += (size_t)26656*168;
  float* G  = ws + off;     off += (size_t)28672*1024;
  float* h0 = ws + off;     off += (size_t)26656*256;
  float* h1 = ws + off;     off += (size_t)26656*256;
  float* h2 = ws + off;     off += (size_t)26656*256;
  (void)ws_size; (void)in_sizes; (void)n_in; (void)out_size;

  levels_k<<<1, 64, 0, stream>>>(train, ism, levs);
  win_x_k<<<17493, 256, 0, stream>>>(train, levs, x0);
  win_out_k<<<2499, 256, 0, stream>>>(train, levs, out + 639744);
  for (int l = 0; l < 4; ++l)
    pack8_k<<<128, 256, 0, stream>>>(whh[l], wpk[l]);

  // layer 0 (d=1): 833 steps, 32 rows -> 32 WGs x 1 row
  proj_mfma<<<dim3(8,209), 256, 0, stream>>>(x0, wih[0], bih[0], bhh[0], G, 26656, 168, 1024, 0, 0);
  srec8_k<1><<<32, 1024, 0, stream>>>(wpk[0], G, h0, nullptr, 833, 1, 32);
  // layer 1 (d=4): 209 steps, 128 rows -> 128 WGs x 1 row
  proj_mfma<<<dim3(8,209), 256, 0, stream>>>(h0, wih[1], bih[1], bhh[1], G, 26752, 256, 1024, 4, 0);
  srec8_k<1><<<128, 1024, 0, stream>>>(wpk[1], G, h1, nullptr, 209, 4, 128);
  // layer 2 (d=16): 53 steps, 512 rows -> 256 WGs x 2 rows
  proj_mfma<<<dim3(8,212), 256, 0, stream>>>(h1, wih[2], bih[2], bhh[2], G, 27136, 256, 1024, 16, 0);
  srec8_k<2><<<256, 1024, 0, stream>>>(wpk[2], G, h2, nullptr, 53, 16, 512);
  // layer 3 (d=64): 14 steps, 2048 rows -> 256 WGs x 8 rows; residual h1; out overwrites h2
  proj_mfma<<<dim3(8,224), 256, 0, stream>>>(h2, wih[3], bih[3], bhh[3], G, 28672, 256, 1024, 64, 0);
  srec8_k<8><<<256, 1024, 0, stream>>>(wpk[3], G, h2, h1, 14, 64, 2048);
  // nonlinear dense: xt = tanh(xf @ nl_w.T + nl_b)  (reuse h0)
  proj_mfma<<<dim3(2,209), 256, 0, stream>>>(h2, nl_w, nl_b, nullptr, h0, 26656, 256, 256, 0, 1);
  // scoring head -> pred (first half of d_out)
  sc_head<<<3332, 256, 0, stream>>>(h0, sc_w, sc_b, out, 26656);
}